// Round 4
// baseline (7787.897 us; speedup 1.0000x reference)
//
#include <hip/hip_runtime.h>
#include <math.h>

#define BATCH 512
#define TM1   31
#define DIMD  256
#define NBLK  256

typedef _Float16 f16;
typedef _Float16 half8 __attribute__((ext_vector_type(8)));
typedef float floatx16 __attribute__((ext_vector_type(16)));

__device__ __forceinline__ float sigmf(float x) { return 1.f / (1.f + __expf(-x)); }

__device__ __forceinline__ float tanh_fast(float x) {
    float ax = fabsf(x);
    float t  = __expf(-2.f * ax);
    float r  = (1.f - t) / (1.f + t);
    return copysignf(r, x);
}

__device__ __forceinline__ void split16(float x, f16* hi, f16* lo) {
    f16 h = (f16)x;
    *hi = h;
    *lo = (f16)(x - (float)h);
}

__device__ __forceinline__ float blockReduceSum256(float v, float* sred) {
#pragma unroll
    for (int m = 32; m > 0; m >>= 1) v += __shfl_xor(v, m);
    __syncthreads();
    if ((threadIdx.x & 63) == 0) sred[threadIdx.x >> 6] = v;
    __syncthreads();
    return sred[0] + sred[1] + sred[2] + sred[3];
}

__device__ __forceinline__ float blockReduceMax256(float v, float* sred) {
#pragma unroll
    for (int m = 32; m > 0; m >>= 1) v = fmaxf(v, __shfl_xor(v, m));
    __syncthreads();
    if ((threadIdx.x & 63) == 0) sred[threadIdx.x >> 6] = v;
    __syncthreads();
    return fmaxf(fmaxf(sred[0], sred[1]), fmaxf(sred[2], sred[3]));
}

// ---------------------------------------------------------------------------
// Device-scope grid barrier (sense = monotonically increasing epoch).
// flags[bid] per-block slot; go broadcast. Agent-scope atomics handle the
// non-coherent per-XCD L2s. Poison (0xAAAAAAAA) != any epoch -> no init.
// ---------------------------------------------------------------------------
__device__ __forceinline__ void grid_barrier(unsigned* flags, unsigned* go, unsigned ep) {
    __syncthreads();
    int bid = blockIdx.x, tid = threadIdx.x;
    if (bid == 0) {
        if (tid > 0 && tid < NBLK) {
            while (__hip_atomic_load(&flags[tid], __ATOMIC_ACQUIRE, __HIP_MEMORY_SCOPE_AGENT) != ep)
                __builtin_amdgcn_s_sleep(1);
        }
        __syncthreads();
        if (tid == 0)
            __hip_atomic_store(go, ep, __ATOMIC_RELEASE, __HIP_MEMORY_SCOPE_AGENT);
    } else {
        if (tid == 0) {
            __hip_atomic_store(&flags[bid], ep, __ATOMIC_RELEASE, __HIP_MEMORY_SCOPE_AGENT);
            while (__hip_atomic_load(go, __ATOMIC_ACQUIRE, __HIP_MEMORY_SCOPE_AGENT) != ep)
                __builtin_amdgcn_s_sleep(1);
        }
        __syncthreads();
    }
}

// ---------------------------------------------------------------------------
// fp16x3 fused MFMA 64x64 tile: C[m,n] = sum_{k in [kbeg,kend)} A[m,k]*W[n,k] (+bias[n])
// Ahi*Whi + Ahi*Wlo + Alo*Whi in one K-loop. XOR-swizzled LDS (conflict-free
// b128), register-prefetch pipeline. (kend-kbeg) % 64 == 0. Validated in R3.
// ---------------------------------------------------------------------------
__device__ __forceinline__ void tile_gemm3(
    const f16* __restrict__ Ahi, const f16* __restrict__ Alo, int lda,
    const f16* __restrict__ Whi, const f16* __restrict__ Wlo, int ldw,
    const float* bias, float* __restrict__ C, int ldc,
    int kbeg, int kend, int m0, int n0, f16* shm)
{
    f16* sAh = shm;
    f16* sAl = shm + 4096;
    f16* sWh = shm + 8192;
    f16* sWl = shm + 12288;
    int tid = threadIdx.x;
    int lane = tid & 63, wid = tid >> 6;
    int wm = wid >> 1, wn = wid & 1;
    int rl = lane & 31, kq = lane >> 5;

    int sr = tid >> 2;
    int g0 = (tid & 3) * 2;
    const f16* pAh = Ahi + (size_t)(m0 + sr) * lda + g0 * 8;
    const f16* pAl = Alo + (size_t)(m0 + sr) * lda + g0 * 8;
    const f16* pWh = Whi + (size_t)(n0 + sr) * ldw + g0 * 8;
    const f16* pWl = Wlo + (size_t)(n0 + sr) * ldw + g0 * 8;
    int s0 = sr * 64 + ((g0 ^ (sr & 7)) * 8);
    int s1 = sr * 64 + (((g0 + 1) ^ (sr & 7)) * 8);

    float4 rAh0 = *(const float4*)(pAh + kbeg);
    float4 rAh1 = *(const float4*)(pAh + kbeg + 8);
    float4 rAl0 = *(const float4*)(pAl + kbeg);
    float4 rAl1 = *(const float4*)(pAl + kbeg + 8);
    float4 rWh0 = *(const float4*)(pWh + kbeg);
    float4 rWh1 = *(const float4*)(pWh + kbeg + 8);
    float4 rWl0 = *(const float4*)(pWl + kbeg);
    float4 rWl1 = *(const float4*)(pWl + kbeg + 8);

    floatx16 acc = {};
    int arow = (wm * 32 + rl) * 64;
    int wrow = (wn * 32 + rl) * 64;
    int sw = (rl & 7);

    for (int k0 = kbeg; k0 < kend; k0 += 64) {
        __syncthreads();
        *(float4*)&sAh[s0] = rAh0; *(float4*)&sAh[s1] = rAh1;
        *(float4*)&sAl[s0] = rAl0; *(float4*)&sAl[s1] = rAl1;
        *(float4*)&sWh[s0] = rWh0; *(float4*)&sWh[s1] = rWh1;
        *(float4*)&sWl[s0] = rWl0; *(float4*)&sWl[s1] = rWl1;
        __syncthreads();
        int kn = k0 + 64;
        if (kn < kend) {
            rAh0 = *(const float4*)(pAh + kn); rAh1 = *(const float4*)(pAh + kn + 8);
            rAl0 = *(const float4*)(pAl + kn); rAl1 = *(const float4*)(pAl + kn + 8);
            rWh0 = *(const float4*)(pWh + kn); rWh1 = *(const float4*)(pWh + kn + 8);
            rWl0 = *(const float4*)(pWl + kn); rWl1 = *(const float4*)(pWl + kn + 8);
        }
#pragma unroll
        for (int ks = 0; ks < 64; ks += 16) {
            int lg = (ks >> 3) + kq;
            int off = ((lg ^ sw) * 8);
            half8 ah = *(const half8*)&sAh[arow + off];
            half8 al = *(const half8*)&sAl[arow + off];
            half8 wh = *(const half8*)&sWh[wrow + off];
            half8 wl = *(const half8*)&sWl[wrow + off];
            acc = __builtin_amdgcn_mfma_f32_32x32x16_f16(ah, wh, acc, 0, 0, 0);
            acc = __builtin_amdgcn_mfma_f32_32x32x16_f16(ah, wl, acc, 0, 0, 0);
            acc = __builtin_amdgcn_mfma_f32_32x32x16_f16(al, wh, acc, 0, 0, 0);
        }
    }

    int col = n0 + wn * 32 + rl;
    float bv = bias ? bias[col] : 0.f;
#pragma unroll
    for (int r = 0; r < 16; ++r) {
        int row = m0 + wm * 32 + (r & 3) + 8 * (r >> 2) + 4 * kq;
        C[(size_t)row * ldc + col] = acc[r] + bv;
    }
}

// ===========================================================================
// ENCODER persistent kernel: 256 blocks x 256 threads. Each block owns 2
// batches (h/c in LDS). Prologue: weight split + t2s. Loop t=0..30:
// [A: finalize t-1 + attention t] barrier [B: gemm tile] barrier. t=31: final
// finalize (enc row 30).
// ===========================================================================
__global__ __launch_bounds__(256, 2) void encoder_kernel(
    const float* __restrict__ inputs,
    const float* __restrict__ eWih, const float* __restrict__ eWhh,
    const float* __restrict__ ebih, const float* __restrict__ ebhh,
    const float* __restrict__ Wc,  const float* __restrict__ bc,
    const float* __restrict__ Wd,  const float* __restrict__ bd,
    const float* __restrict__ Wa,  const float* __restrict__ ba,
    const float* __restrict__ dW1, const float* __restrict__ dWhh,
    const float* __restrict__ dbih, const float* __restrict__ dbhh,
    float* __restrict__ t2s, float* __restrict__ g_enc,
    f16* __restrict__ Ahi, f16* __restrict__ Alo,
    f16* __restrict__ enchi, f16* __restrict__ enclo,
    f16* __restrict__ eWhi, f16* __restrict__ eWlo,
    f16* __restrict__ dWchi, f16* __restrict__ dWclo,
    f16* __restrict__ Vwhi, f16* __restrict__ Vwlo,
    float* __restrict__ ebcomb, float* __restrict__ dbias,
    unsigned* __restrict__ bflags, unsigned* __restrict__ bgo)
{
    __shared__ float sh_hc[2][1024];
    __shared__ float t1s[32];
    __shared__ float sred[4];
    __shared__ __align__(16) char smem[32768];   // union: xbuf (31744B) | gemm staging (32768B)

    int bid = blockIdx.x, tid = threadIdx.x;
    int gidx = bid * 256 + tid;

    // ---------------- prologue: weight splits ----------------
    for (size_t i = gidx; i < 2048u * 768u; i += 65536) {
        int n = (int)(i / 768), k = (int)(i - (size_t)n * 768);
        float v = (k < 256) ? eWih[n * 256 + k] : eWhh[n * 512 + (k - 256)];
        split16(v, &eWhi[i], &eWlo[i]);
    }
    for (size_t i = gidx; i < 2560u * 1024u; i += 65536) {
        int n = (int)(i >> 10), k = (int)(i & 1023);
        float v;
        if (n < 512)      v = dW1[n * 1536 + k];
        else if (k < 512) v = dWhh[(n - 512) * 512 + k];
        else              v = 0.f;
        split16(v, &dWchi[i], &dWclo[i]);
    }
    for (size_t i = gidx; i < 512u * 512u; i += 65536) {
        int n = (int)(i >> 9), k = (int)(i & 511);
        split16(dW1[n * 1536 + 1024 + k], &Vwhi[i], &Vwlo[i]);
    }
    for (int i = gidx; i < 2048; i += 65536) ebcomb[i] = ebih[i] + ebhh[i];
    for (int i = gidx; i < 2560; i += 65536)
        dbias[i] = (i < 512) ? 0.f : (dbih[i - 512] + dbhh[i - 512]);

    // ---------------- prologue: t2s for 2 owned batches ----------------
    float* xbuf = (float*)smem;
    for (int bb = 0; bb < 2; ++bb) {
        int b = 2 * bid + bb;
        for (int i = tid; i < 7936; i += 256)
            xbuf[i] = inputs[((size_t)b * TM1 + (i >> 8)) * 257 + 1 + (i & 255)];
        __syncthreads();
        for (int pos = tid; pos < 7936; pos += 256) {
            int s = pos >> 8, d = pos & 255;
            float acc = bd[s];
            for (int u = 0; u < TM1; ++u) acc += xbuf[u * 256 + d] * Wd[s * TM1 + u];
            t2s[((size_t)b * TM1 + s) * 256 + d] = acc;
        }
        __syncthreads();
    }
    // zero h/c state; zero A h-part for step 0
    for (int j = tid; j < 2048; j += 256) ((float*)sh_hc)[j] = 0.f;
    for (int bb = 0; bb < 2; ++bb) {
        int b = 2 * bid + bb;
        for (int e = tid; e < 512; e += 256) {
            Ahi[b * 768 + 256 + e] = (f16)0.f;
            Alo[b * 768 + 256 + e] = (f16)0.f;
        }
    }
    __syncthreads();

    // ---------------- main loop ----------------
    unsigned ep = 0;
    int m0 = (bid & 7) * 64, n0 = (bid >> 3) * 64;

    for (int t = 0; t <= TM1; ++t) {
        // ---- phase A: finalize LSTM of step t-1 ----
        if (t > 0) {
            for (int bb = 0; bb < 2; ++bb) {
                int b = 2 * bid + bb;
                for (int e = tid; e < 512; e += 256) {
                    float gi = g_enc[b * 2048 + e];
                    float gf = g_enc[b * 2048 + 512 + e];
                    float gg = g_enc[b * 2048 + 1024 + e];
                    float go_ = g_enc[b * 2048 + 1536 + e];
                    float cp = sh_hc[bb][512 + e];
                    float c2 = sigmf(gf) * cp + sigmf(gi) * tanh_fast(gg);
                    float h2 = sigmf(go_) * tanh_fast(c2);
                    sh_hc[bb][e] = h2;
                    sh_hc[bb][512 + e] = c2;
                    size_t eo = ((size_t)b * TM1 + (t - 1)) * 512 + e;
                    split16(h2, &enchi[eo], &enclo[eo]);
                    if (t < TM1) {
                        split16(h2, &Ahi[b * 768 + 256 + e], &Alo[b * 768 + 256 + e]);
                    }
                }
            }
        }
        if (t == TM1) break;
        __syncthreads();

        // ---- phase A: attention for step t (per owned batch) ----
        for (int bb = 0; bb < 2; ++bb) {
            int b = 2 * bid + bb;
            if (tid < 248) {
                int s = tid >> 3, l8 = tid & 7;
                const float* wrow = Wc + s * 1024;
                const float* hcp = &sh_hc[bb][0];
                float p = 0.f;
                for (int j = l8 * 4; j < 1024; j += 32) {
                    float4 w4 = *(const float4*)(wrow + j);
                    float4 h4 = *(const float4*)(hcp + j);
                    p += w4.x * h4.x + w4.y * h4.y + w4.z * h4.z + w4.w * h4.w;
                }
                p += __shfl_xor(p, 1); p += __shfl_xor(p, 2); p += __shfl_xor(p, 4);
                if (l8 == 0) t1s[s] = p + bc[s];
            }
            __syncthreads();
            float sc = ba[0];
            const float* t2p = t2s + ((size_t)b * TM1) * 256 + tid;
            for (int s = 0; s < TM1; ++s)
                sc += tanh_fast(t1s[s] + t2p[s * 256]) * Wa[s];
            float mx = blockReduceMax256(sc, sred);
            float ex = __expf(sc - mx);
            float sm = blockReduceSum256(ex, sred);
            float w = (ex / sm) * inputs[((size_t)b * TM1 + t) * 257 + 1 + tid];
            split16(w, &Ahi[b * 768 + tid], &Alo[b * 768 + tid]);
            __syncthreads();
        }

        grid_barrier(bflags, bgo, ++ep);

        // ---- phase B: gemm tile (A [512x768] @ eW^T -> g [512x2048]) ----
        tile_gemm3(Ahi, Alo, 768, eWhi, eWlo, 768, ebcomb,
                   g_enc, 2048, 0, 768, m0, n0, (f16*)smem);

        grid_barrier(bflags, bgo, ++ep);
    }
}

// ===========================================================================
// DECODER persistent kernel: prologue V-gemm; loop: [A: attention+pointwise]
// barrier [B: gemm u/gh] barrier; epilogue final FC.
// ===========================================================================
__global__ __launch_bounds__(256, 2) void decoder_kernel(
    const float* __restrict__ inputs,
    const float* __restrict__ dW2, const float* __restrict__ db2,
    const float* __restrict__ fcW, const float* __restrict__ fcb,
    const float* __restrict__ dWih,
    const float* __restrict__ fcfW, const float* __restrict__ fcfb,
    float* __restrict__ out,
    float* __restrict__ V, float* __restrict__ gu, float* __restrict__ gu2,
    f16* __restrict__ hdhi, f16* __restrict__ hdlo,
    const f16* __restrict__ enchi, const f16* __restrict__ enclo,
    const f16* __restrict__ dWchi, const f16* __restrict__ dWclo,
    const f16* __restrict__ Vwhi, const f16* __restrict__ Vwlo,
    const float* __restrict__ db1, const float* __restrict__ dbias,
    unsigned* __restrict__ bflags, unsigned* __restrict__ bgo)
{
    __shared__ float sh_hc[2][1024];
    __shared__ float ctxL[2][512];
    __shared__ float su[512];
    __shared__ float sw2[512];
    __shared__ float satt[32];
    __shared__ float sred[4];
    __shared__ __align__(16) char smem[32768];

    int bid = blockIdx.x, tid = threadIdx.x;

    // ---------------- prologue ----------------
    for (int j = tid; j < 2048; j += 256) ((float*)sh_hc)[j] = 0.f;
    for (int j = tid; j < 512; j += 256) sw2[j] = dW2[j];
    __syncthreads();

    // V = enc_out @ dec_W1[:,1024:]^T + b1   (15872 x 512, 1984 tiles)
    for (int tt = bid; tt < 1984; tt += NBLK) {
        int mi = tt >> 3, ni = tt & 7;
        tile_gemm3(enchi, enclo, 512, Vwhi, Vwlo, 512, db1,
                   V, 512, 0, 512, mi * 64, ni * 64, (f16*)smem);
    }

    unsigned ep = 0;
    grid_barrier(bflags, bgo, ++ep);

    // ---------------- main loop ----------------
    for (int t = 0; t < TM1; ++t) {
        // ---- phase A: attention + pointwise for 2 owned batches ----
        for (int bb = 0; bb < 2; ++bb) {
            int b = 2 * bid + bb;
            for (int e = tid; e < 512; e += 256)
                su[e] = t ? (gu[(size_t)b * 2560 + e] + gu2[(size_t)b * 512 + e]) : 0.f;
            __syncthreads();
            if (tid < 248) {
                int tp = tid >> 3, l8 = tid & 7;
                const float* vrow = V + ((size_t)b * TM1 + tp) * 512;
                float p = 0.f;
                for (int j = l8 * 4; j < 512; j += 32) {
                    float4 v4 = *(const float4*)(vrow + j);
                    p += tanh_fast(su[j + 0] + v4.x) * sw2[j + 0]
                       + tanh_fast(su[j + 1] + v4.y) * sw2[j + 1]
                       + tanh_fast(su[j + 2] + v4.z) * sw2[j + 2]
                       + tanh_fast(su[j + 3] + v4.w) * sw2[j + 3];
                }
                p += __shfl_xor(p, 1); p += __shfl_xor(p, 2); p += __shfl_xor(p, 4);
                if (l8 == 0) satt[tp] = p + db2[0];
            }
            __syncthreads();
            if (tid < 64) {
                float v = (tid < TM1) ? satt[tid] : -3.4e38f;
                float m = v;
#pragma unroll
                for (int k = 32; k > 0; k >>= 1) m = fmaxf(m, __shfl_xor(m, k));
                float e = (tid < TM1) ? __expf(v - m) : 0.f;
                float s = e;
#pragma unroll
                for (int k = 32; k > 0; k >>= 1) s += __shfl_xor(s, k);
                if (tid < TM1) satt[tid] = e / s;
            }
            __syncthreads();

            float part = 0.f;
#pragma unroll
            for (int r = 0; r < 2; ++r) {
                int e = tid + r * 256;
                float cx = 0.f;
                const f16* eh = enchi + ((size_t)b * TM1) * 512 + e;
                const f16* el = enclo + ((size_t)b * TM1) * 512 + e;
                for (int tp = 0; tp < TM1; ++tp)
                    cx += satt[tp] * ((float)eh[tp * 512] + (float)el[tp * 512]);
                ctxL[bb][e] = cx;
                part += cx * fcW[e];
            }
            float ysum = blockReduceSum256(part, sred);
            float y_til = ysum + inputs[((size_t)b * TM1 + t) * 257] * fcW[512] + fcb[0];

            for (int e = tid; e < 512; e += 256) {
                float gi = (t ? gu[(size_t)b * 2560 + 512 + e]  : dbias[512 + e])  + y_til * dWih[e];
                float gf = (t ? gu[(size_t)b * 2560 + 1024 + e] : dbias[1024 + e]) + y_til * dWih[512 + e];
                float gg = (t ? gu[(size_t)b * 2560 + 1536 + e] : dbias[1536 + e]) + y_til * dWih[1024 + e];
                float go_ = (t ? gu[(size_t)b * 2560 + 2048 + e] : dbias[2048 + e]) + y_til * dWih[1536 + e];
                float cp = sh_hc[bb][512 + e];
                float c2 = sigmf(gf) * cp + sigmf(gi) * tanh_fast(gg);
                float h2 = sigmf(go_) * tanh_fast(c2);
                sh_hc[bb][e] = h2;
                sh_hc[bb][512 + e] = c2;
                split16(h2, &hdhi[(size_t)b * 1024 + e], &hdlo[(size_t)b * 1024 + e]);
                split16(c2, &hdhi[(size_t)b * 1024 + 512 + e], &hdlo[(size_t)b * 1024 + 512 + e]);
            }
            __syncthreads();
        }

        if (t == TM1 - 1) break;

        grid_barrier(bflags, bgo, ++ep);

        // ---- phase B: gemm for step t+1: u = [h|c]@dW1part^T, gh = h@Whh^T ----
        for (int tt = bid; tt < 384; tt += NBLK) {
            if (tt < 256) {
                int m0 = (tt & 7) * 64, n0 = 512 + (tt >> 3) * 64;
                tile_gemm3(hdhi, hdlo, 1024, dWchi, dWclo, 1024, dbias,
                           gu, 2560, 0, 512, m0, n0, (f16*)smem);
            } else {
                int idx = tt - 256;
                int m0 = (idx & 7) * 64, n0 = ((idx >> 3) & 7) * 64, kh = idx >> 6;
                if (kh == 0)
                    tile_gemm3(hdhi, hdlo, 1024, dWchi, dWclo, 1024, dbias,
                               gu, 2560, 0, 512, m0, n0, (f16*)smem);
                else
                    tile_gemm3(hdhi, hdlo, 1024, dWchi, dWclo, 1024, nullptr,
                               gu2, 512, 512, 1024, m0, n0, (f16*)smem);
            }
        }

        grid_barrier(bflags, bgo, ++ep);
    }

    // ---------------- epilogue: out[b] = [h31|ctx30] . fcfW + fcfb ----------------
    for (int bb = 0; bb < 2; ++bb) {
        float p = 0.f;
        for (int e = tid; e < 512; e += 256)
            p += sh_hc[bb][e] * fcfW[e] + ctxL[bb][e] * fcfW[512 + e];
        float s = blockReduceSum256(p, sred);
        if (tid == 0) out[2 * bid + bb] = s + fcfb[0];
        __syncthreads();
    }
}

extern "C" void kernel_launch(void* const* d_in, const int* in_sizes, int n_in,
                              void* d_out, int out_size, void* d_ws, size_t ws_size,
                              hipStream_t stream) {
    const float* inputs  = (const float*)d_in[0];
    const float* eWih    = (const float*)d_in[1];
    const float* eWhh    = (const float*)d_in[2];
    const float* ebih    = (const float*)d_in[3];
    const float* ebhh    = (const float*)d_in[4];
    const float* eWc     = (const float*)d_in[5];
    const float* ebc     = (const float*)d_in[6];
    const float* eWd     = (const float*)d_in[7];
    const float* ebd     = (const float*)d_in[8];
    const float* eWa     = (const float*)d_in[9];
    const float* eba     = (const float*)d_in[10];
    const float* dW1     = (const float*)d_in[11];
    const float* db1     = (const float*)d_in[12];
    const float* dW2     = (const float*)d_in[13];
    const float* db2     = (const float*)d_in[14];
    const float* dWih    = (const float*)d_in[15];
    const float* dWhh    = (const float*)d_in[16];
    const float* dbih    = (const float*)d_in[17];
    const float* dbhh    = (const float*)d_in[18];
    const float* fcW     = (const float*)d_in[19];
    const float* fcb     = (const float*)d_in[20];
    const float* fcfW    = (const float*)d_in[21];
    const float* fcfb    = (const float*)d_in[22];
    float* out = (float*)d_out;

    // -------- workspace layout (phase-overlapped union; ~91 MB) --------
    float* scr = (float*)d_ws;
    // encoder view of union
    float* t2s    = scr;                        // 4,063,232 f
    float* g_enc  = scr + 4063232;              // 1,048,576 f
    f16*   Ahi    = (f16*)(scr + 5111808);      //   393,216 h
    f16*   Alo    = Ahi + 393216;               //   393,216 h
    // decoder view of union (encoder scratch dead by then)
    float* V      = scr;                        // 8,126,464 f
    float* gu     = scr + 8126464;              // 1,310,720 f
    float* gu2    = scr + 9437184;              //   262,144 f
    // persistent
    float* P      = scr + 9699328;
    f16* hdhi  = (f16*)P;                       //   524,288 h
    f16* hdlo  = hdhi + 524288;                 //   524,288 h
    float* P2  = P + 524288;
    f16* enchi = (f16*)P2;                      // 8,126,464 h
    f16* enclo = enchi + 8126464;
    float* P3  = P2 + 8126464;
    f16* eWhi  = (f16*)P3;                      // 1,572,864 h
    f16* eWlo  = eWhi + 1572864;
    float* P4  = P3 + 1572864;
    f16* dWchi = (f16*)P4;                      // 2,621,440 h
    f16* dWclo = dWchi + 2621440;
    float* P5  = P4 + 2621440;
    f16* Vwhi  = (f16*)P5;                      //   262,144 h
    f16* Vwlo  = Vwhi + 262144;
    float* P6  = P5 + 262144;
    float* ebcomb = P6;                         // 2,048 f
    float* dbias  = P6 + 2048;                  // 2,560 f
    unsigned* encF = (unsigned*)(P6 + 4608);    // 256 + pad
    unsigned* encG = encF + 320;
    unsigned* decF = encF + 384;
    unsigned* decG = encF + 704;

    hipLaunchKernelGGL(encoder_kernel, dim3(NBLK), dim3(256), 0, stream,
                       inputs, eWih, eWhh, ebih, ebhh, eWc, ebc, eWd, ebd, eWa, eba,
                       dW1, dWhh, dbih, dbhh,
                       t2s, g_enc, Ahi, Alo, enchi, enclo,
                       eWhi, eWlo, dWchi, dWclo, Vwhi, Vwlo, ebcomb, dbias,
                       encF, encG);

    hipLaunchKernelGGL(decoder_kernel, dim3(NBLK), dim3(256), 0, stream,
                       inputs, dW2, db2, fcW, fcb, dWih, fcfW, fcfb, out,
                       V, gu, gu2, hdhi, hdlo, enchi, enclo,
                       dWchi, dWclo, Vwhi, Vwlo, db1, dbias,
                       decF, decG);
}

// Round 5
// 2261.650 us; speedup vs baseline: 3.4435x; 3.4435x over previous
//
#include <hip/hip_runtime.h>
#include <math.h>

#define BATCH 512
#define TM1   31
#define DIMD  256

typedef _Float16 f16;
typedef _Float16 half8 __attribute__((ext_vector_type(8)));
typedef float floatx16 __attribute__((ext_vector_type(16)));

__device__ __forceinline__ float sigmf(float x) { return 1.f / (1.f + __expf(-x)); }

__device__ __forceinline__ float tanh_fast(float x) {
    float ax = fabsf(x);
    float t  = __expf(-2.f * ax);
    float r  = (1.f - t) / (1.f + t);
    return copysignf(r, x);
}

__device__ __forceinline__ void split16(float x, f16* hi, f16* lo) {
    f16 h = (f16)x;
    *hi = h;
    *lo = (f16)(x - (float)h);
}

__device__ __forceinline__ float blockReduceSum256(float v, float* sred) {
#pragma unroll
    for (int m = 32; m > 0; m >>= 1) v += __shfl_xor(v, m);
    __syncthreads();
    if ((threadIdx.x & 63) == 0) sred[threadIdx.x >> 6] = v;
    __syncthreads();
    return sred[0] + sred[1] + sred[2] + sred[3];
}

__device__ __forceinline__ float blockReduceMax256(float v, float* sred) {
#pragma unroll
    for (int m = 32; m > 0; m >>= 1) v = fmaxf(v, __shfl_xor(v, m));
    __syncthreads();
    if ((threadIdx.x & 63) == 0) sred[threadIdx.x >> 6] = v;
    __syncthreads();
    return fmaxf(fmaxf(sred[0], sred[1]), fmaxf(sred[2], sred[3]));
}

// ---------------------------------------------------------------------------
// prep: split weights into fp16 hi/lo pairs; combined biases.
// ---------------------------------------------------------------------------
__global__ __launch_bounds__(256) void prep_kernel(
    const float* __restrict__ eWih, const float* __restrict__ eWhh,
    const float* __restrict__ ebih, const float* __restrict__ ebhh,
    const float* __restrict__ dW1,  const float* __restrict__ dWhh,
    const float* __restrict__ dbih, const float* __restrict__ dbhh,
    f16* __restrict__ eWhi, f16* __restrict__ eWlo,
    f16* __restrict__ dWchi, f16* __restrict__ dWclo,
    f16* __restrict__ Vwhi, f16* __restrict__ Vwlo,
    float* __restrict__ ebcomb, float* __restrict__ dbias)
{
    int idx = blockIdx.x * blockDim.x + threadIdx.x;
    int stride = gridDim.x * blockDim.x;
    for (int i = idx; i < 2048 * 768; i += stride) {
        int n = i / 768, k = i - n * 768;
        float v = (k < 256) ? eWih[n * 256 + k] : eWhh[n * 512 + (k - 256)];
        split16(v, &eWhi[i], &eWlo[i]);
    }
    for (int i = idx; i < 2560 * 1024; i += stride) {
        int n = i >> 10, k = i & 1023;
        float v;
        if (n < 512)      v = dW1[n * 1536 + k];
        else if (k < 512) v = dWhh[(n - 512) * 512 + k];
        else              v = 0.f;
        split16(v, &dWchi[i], &dWclo[i]);
    }
    for (int i = idx; i < 512 * 512; i += stride) {
        int n = i >> 9, k = i & 511;
        split16(dW1[n * 1536 + 1024 + k], &Vwhi[i], &Vwlo[i]);
    }
    for (int i = idx; i < 2048; i += stride) ebcomb[i] = ebih[i] + ebhh[i];
    for (int i = idx; i < 2560; i += stride)
        dbias[i] = (i < 512) ? 0.f : (dbih[i - 512] + dbhh[i - 512]);
}

// ---------------------------------------------------------------------------
// t2s[b][s][d] = sum_t X[b,t,d]*Wd[s,t] + bd[s]
// ---------------------------------------------------------------------------
__global__ __launch_bounds__(256) void t2s_kernel(
    const float* __restrict__ inputs, const float* __restrict__ Wd,
    const float* __restrict__ bd, float* __restrict__ t2s) {
    __shared__ float sX[TM1 * DIMD];
    __shared__ float sWd[TM1 * TM1];
    int b = blockIdx.x, tid = threadIdx.x;
    for (int i = tid; i < TM1 * DIMD; i += 256) {
        int tt = i >> 8, d = i & 255;
        sX[i] = inputs[(b * TM1 + tt) * 257 + 1 + d];
    }
    for (int i = tid; i < TM1 * TM1; i += 256) sWd[i] = Wd[i];
    __syncthreads();
    int d = tid;
    for (int s = 0; s < TM1; s++) {
        float acc = bd[s];
        for (int tt = 0; tt < TM1; tt++) acc += sX[tt * DIMD + d] * sWd[s * TM1 + tt];
        t2s[(b * TM1 + s) * DIMD + d] = acc;
    }
}

// ---------------------------------------------------------------------------
// fp16x3 fused MFMA GEMM (validated R3): C[m,n] = sum_k A[m,k]*W[n,k] + bias[n]
// One K-loop: Ahi*Whi + Ahi*Wlo + Alo*Whi. 64x64 tile, 4 waves of 32x32
// (mfma_32x32x16_f16), BK=64, XOR-swizzled LDS (conflict-free b128),
// register-prefetch pipeline. kend = (n0 >= nsplit) ? 512 : K.
// ---------------------------------------------------------------------------
__global__ __launch_bounds__(256) void gemm3f(
    const f16* __restrict__ Ahi, const f16* __restrict__ Alo, int lda,
    const f16* __restrict__ Whi, const f16* __restrict__ Wlo, int ldw,
    const float* __restrict__ bias, float* __restrict__ C, int ldc,
    int K, int nsplit)
{
    __shared__ f16 sAh[64 * 64];
    __shared__ f16 sAl[64 * 64];
    __shared__ f16 sWh[64 * 64];
    __shared__ f16 sWl[64 * 64];
    int tid = threadIdx.x;
    int n0 = blockIdx.x * 64, m0 = blockIdx.y * 64;
    int kend = (n0 >= nsplit) ? 512 : K;
    int lane = tid & 63, wid = tid >> 6;
    int wm = wid >> 1, wn = wid & 1;
    int rl = lane & 31, kq = lane >> 5;

    int sr = tid >> 2;
    int g0 = (tid & 3) * 2;
    const f16* pAh = Ahi + (size_t)(m0 + sr) * lda + g0 * 8;
    const f16* pAl = Alo + (size_t)(m0 + sr) * lda + g0 * 8;
    const f16* pWh = Whi + (size_t)(n0 + sr) * ldw + g0 * 8;
    const f16* pWl = Wlo + (size_t)(n0 + sr) * ldw + g0 * 8;
    int s0 = sr * 64 + ((g0 ^ (sr & 7)) * 8);
    int s1 = sr * 64 + (((g0 + 1) ^ (sr & 7)) * 8);

    float4 rAh0 = *(const float4*)(pAh);
    float4 rAh1 = *(const float4*)(pAh + 8);
    float4 rAl0 = *(const float4*)(pAl);
    float4 rAl1 = *(const float4*)(pAl + 8);
    float4 rWh0 = *(const float4*)(pWh);
    float4 rWh1 = *(const float4*)(pWh + 8);
    float4 rWl0 = *(const float4*)(pWl);
    float4 rWl1 = *(const float4*)(pWl + 8);

    floatx16 acc = {};
    int arow = (wm * 32 + rl) * 64;
    int wrow = (wn * 32 + rl) * 64;
    int sw = (rl & 7);

    for (int k0 = 0; k0 < kend; k0 += 64) {
        __syncthreads();
        *(float4*)&sAh[s0] = rAh0; *(float4*)&sAh[s1] = rAh1;
        *(float4*)&sAl[s0] = rAl0; *(float4*)&sAl[s1] = rAl1;
        *(float4*)&sWh[s0] = rWh0; *(float4*)&sWh[s1] = rWh1;
        *(float4*)&sWl[s0] = rWl0; *(float4*)&sWl[s1] = rWl1;
        __syncthreads();
        int kn = k0 + 64;
        if (kn < kend) {
            rAh0 = *(const float4*)(pAh + kn); rAh1 = *(const float4*)(pAh + kn + 8);
            rAl0 = *(const float4*)(pAl + kn); rAl1 = *(const float4*)(pAl + kn + 8);
            rWh0 = *(const float4*)(pWh + kn); rWh1 = *(const float4*)(pWh + kn + 8);
            rWl0 = *(const float4*)(pWl + kn); rWl1 = *(const float4*)(pWl + kn + 8);
        }
#pragma unroll
        for (int ks = 0; ks < 64; ks += 16) {
            int lg = (ks >> 3) + kq;
            int off = ((lg ^ sw) * 8);
            half8 ah = *(const half8*)&sAh[arow + off];
            half8 al = *(const half8*)&sAl[arow + off];
            half8 wh = *(const half8*)&sWh[wrow + off];
            half8 wl = *(const half8*)&sWl[wrow + off];
            acc = __builtin_amdgcn_mfma_f32_32x32x16_f16(ah, wh, acc, 0, 0, 0);
            acc = __builtin_amdgcn_mfma_f32_32x32x16_f16(ah, wl, acc, 0, 0, 0);
            acc = __builtin_amdgcn_mfma_f32_32x32x16_f16(al, wh, acc, 0, 0, 0);
        }
    }

    int col = n0 + wn * 32 + rl;
    float bv = bias[col];
#pragma unroll
    for (int r = 0; r < 16; ++r) {
        int row = m0 + wm * 32 + (r & 3) + 8 * (r >> 2) + 4 * kq;
        C[(size_t)row * ldc + col] = acc[r] + bv;
    }
}

// ---------------------------------------------------------------------------
// Encoder step: 512 blocks, one batch per block (full-chip parallelism —
// the 64-block variant measured 48us at 2.4% occupancy; this shape never
// bottlenecked in R2). Finalize LSTM t-1, then attention t.
// ---------------------------------------------------------------------------
__global__ __launch_bounds__(256) void enc_step_kernel(
    const float* __restrict__ inputs, const float* __restrict__ t2s,
    const float* __restrict__ Wc, const float* __restrict__ bc,
    const float* __restrict__ Wa, const float* __restrict__ ba,
    const float* __restrict__ g, float* __restrict__ hc,
    f16* __restrict__ Ahi, f16* __restrict__ Alo,
    f16* __restrict__ enchi, f16* __restrict__ enclo,
    float* __restrict__ hc_dec, f16* __restrict__ hdhi, f16* __restrict__ hdlo,
    int t) {
    __shared__ float sh_hc[1024];
    __shared__ float t1s[32];
    __shared__ float sred[4];
    int b = blockIdx.x, tid = threadIdx.x;

    if (t > 0) {
        for (int e = tid; e < 512; e += 256) {
            float gi = g[b * 2048 + e];
            float gf = g[b * 2048 + 512 + e];
            float gg = g[b * 2048 + 1024 + e];
            float go = g[b * 2048 + 1536 + e];
            float cp = hc[b * 1024 + 512 + e];
            float c2 = sigmf(gf) * cp + sigmf(gi) * tanh_fast(gg);
            float h2 = sigmf(go) * tanh_fast(c2);
            hc[b * 1024 + e] = h2;
            hc[b * 1024 + 512 + e] = c2;
            sh_hc[e] = h2;
            sh_hc[512 + e] = c2;
            size_t eo = ((size_t)b * TM1 + (t - 1)) * 512 + e;
            split16(h2, &enchi[eo], &enclo[eo]);
        }
    } else {
        for (int j = tid; j < 1024; j += 256) { sh_hc[j] = 0.f; hc[b * 1024 + j] = 0.f; }
    }
    if (t == TM1) {
        for (int j = tid; j < 1024; j += 256) {
            hc_dec[b * 1024 + j] = 0.f;
            hdhi[b * 1024 + j] = (f16)0.f;
            hdlo[b * 1024 + j] = (f16)0.f;
        }
        return;
    }
    __syncthreads();

    // t1[s] = [h|c].Wc[s] + bc[s]  (8 lanes per s, float4 loads)
    if (tid < 248) {
        int s = tid >> 3, l8 = tid & 7;
        const float* wrow = Wc + s * 1024;
        float p = 0.f;
        for (int j = l8 * 4; j < 1024; j += 32) {
            float4 w4 = *(const float4*)(wrow + j);
            float4 h4 = *(const float4*)(&sh_hc[j]);
            p += w4.x * h4.x + w4.y * h4.y + w4.z * h4.z + w4.w * h4.w;
        }
        p += __shfl_xor(p, 1); p += __shfl_xor(p, 2); p += __shfl_xor(p, 4);
        if (l8 == 0) t1s[s] = p + bc[s];
    }
    __syncthreads();

    // score + softmax over d (one thread per d)
    int d = tid;
    float sc = ba[0];
    const float* t2p = t2s + ((size_t)b * TM1) * DIMD + d;
    for (int s = 0; s < TM1; s++) sc += tanh_fast(t1s[s] + t2p[s * DIMD]) * Wa[s];
    float mx = blockReduceMax256(sc, sred);
    float ex = __expf(sc - mx);
    float sm = blockReduceSum256(ex, sred);
    float w = (ex / sm) * inputs[((size_t)b * TM1 + t) * 257 + 1 + d];
    split16(w, &Ahi[b * 768 + d], &Alo[b * 768 + d]);
    for (int j = tid; j < 512; j += 256)
        split16(sh_hc[j], &Ahi[b * 768 + 256 + j], &Alo[b * 768 + 256 + j]);
}

// ---------------------------------------------------------------------------
// Decoder step: temporal attention + ctx + y_tilde + LSTM pointwise.
// ---------------------------------------------------------------------------
__global__ __launch_bounds__(256) void dec_step_kernel(
    const float* __restrict__ inputs, const float* __restrict__ V,
    const float* __restrict__ W2, const float* __restrict__ b2,
    const f16* __restrict__ enchi, const f16* __restrict__ enclo,
    const float* __restrict__ fcW, const float* __restrict__ fcb,
    const float* __restrict__ Wih, const float* __restrict__ gu,
    float* __restrict__ hc, f16* __restrict__ hdhi, f16* __restrict__ hdlo,
    float* __restrict__ ctx, int t) {
    __shared__ float su[512];
    __shared__ float sw2[512];
    __shared__ float s_att[TM1];
    __shared__ float sred[4];
    int b = blockIdx.x, tid = threadIdx.x;
    for (int e = tid; e < 512; e += 256) {
        su[e]  = gu[(size_t)b * 2560 + e];
        sw2[e] = W2[e];
    }
    __syncthreads();
    if (tid < 248) {
        int tp = tid >> 3, l8 = tid & 7;
        const float* vrow = V + ((size_t)b * TM1 + tp) * 512;
        float p = 0.f;
        for (int j = l8 * 4; j < 512; j += 32) {
            float4 v4 = *(const float4*)(vrow + j);
            p += tanh_fast(su[j + 0] + v4.x) * sw2[j + 0]
               + tanh_fast(su[j + 1] + v4.y) * sw2[j + 1]
               + tanh_fast(su[j + 2] + v4.z) * sw2[j + 2]
               + tanh_fast(su[j + 3] + v4.w) * sw2[j + 3];
        }
        p += __shfl_xor(p, 1); p += __shfl_xor(p, 2); p += __shfl_xor(p, 4);
        if (l8 == 0) s_att[tp] = p + b2[0];
    }
    __syncthreads();
    if (tid < 64) {
        float v = (tid < TM1) ? s_att[tid] : -3.4e38f;
        float m = v;
#pragma unroll
        for (int k = 32; k > 0; k >>= 1) m = fmaxf(m, __shfl_xor(m, k));
        float e = (tid < TM1) ? __expf(v - m) : 0.f;
        float s = e;
#pragma unroll
        for (int k = 32; k > 0; k >>= 1) s += __shfl_xor(s, k);
        if (tid < TM1) s_att[tid] = e / s;
    }
    __syncthreads();

    float part = 0.f;
#pragma unroll
    for (int r = 0; r < 2; r++) {
        int e = tid + r * 256;
        float cx = 0.f;
        const f16* eh = enchi + (size_t)b * TM1 * 512 + e;
        const f16* el = enclo + (size_t)b * TM1 * 512 + e;
        for (int tp = 0; tp < TM1; tp++)
            cx += s_att[tp] * ((float)eh[tp * 512] + (float)el[tp * 512]);
        ctx[b * 512 + e] = cx;
        part += cx * fcW[e];
    }
    float y = inputs[((size_t)b * TM1 + t) * 257];
    float ysum = blockReduceSum256(part, sred);
    float y_til = ysum + y * fcW[512] + fcb[0];

    for (int e = tid; e < 512; e += 256) {
        float gi = gu[(size_t)b * 2560 + 512 + e]  + y_til * Wih[e];
        float gf = gu[(size_t)b * 2560 + 1024 + e] + y_til * Wih[512 + e];
        float gg = gu[(size_t)b * 2560 + 1536 + e] + y_til * Wih[1024 + e];
        float go = gu[(size_t)b * 2560 + 2048 + e] + y_til * Wih[1536 + e];
        float cp = hc[b * 1024 + 512 + e];
        float c2 = sigmf(gf) * cp + sigmf(gi) * tanh_fast(gg);
        float h2 = sigmf(go) * tanh_fast(c2);
        hc[b * 1024 + e] = h2;
        hc[b * 1024 + 512 + e] = c2;
        split16(h2, &hdhi[(size_t)b * 1024 + e], &hdlo[(size_t)b * 1024 + e]);
        split16(c2, &hdhi[(size_t)b * 1024 + 512 + e], &hdlo[(size_t)b * 1024 + 512 + e]);
    }
}

__global__ __launch_bounds__(256) void final_kernel(
    const float* __restrict__ hc, const float* __restrict__ ctx,
    const float* __restrict__ fcfW, const float* __restrict__ fcfb,
    float* __restrict__ out) {
    __shared__ float sred[4];
    int b = blockIdx.x, tid = threadIdx.x;
    float p = 0.f;
    for (int e = tid; e < 512; e += 256)
        p += hc[b * 1024 + e] * fcfW[e] + ctx[b * 512 + e] * fcfW[512 + e];
    float s = blockReduceSum256(p, sred);
    if (tid == 0) out[b] = s + fcfb[0];
}

extern "C" void kernel_launch(void* const* d_in, const int* in_sizes, int n_in,
                              void* d_out, int out_size, void* d_ws, size_t ws_size,
                              hipStream_t stream) {
    const float* inputs  = (const float*)d_in[0];
    const float* eWih    = (const float*)d_in[1];
    const float* eWhh    = (const float*)d_in[2];
    const float* ebih    = (const float*)d_in[3];
    const float* ebhh    = (const float*)d_in[4];
    const float* eWc     = (const float*)d_in[5];
    const float* ebc     = (const float*)d_in[6];
    const float* eWd     = (const float*)d_in[7];
    const float* ebd     = (const float*)d_in[8];
    const float* eWa     = (const float*)d_in[9];
    const float* eba     = (const float*)d_in[10];
    const float* dW1     = (const float*)d_in[11];
    const float* db1     = (const float*)d_in[12];
    const float* dW2     = (const float*)d_in[13];
    const float* db2     = (const float*)d_in[14];
    const float* dWih    = (const float*)d_in[15];
    const float* dWhh    = (const float*)d_in[16];
    const float* dbih    = (const float*)d_in[17];
    const float* dbhh    = (const float*)d_in[18];
    const float* fcW     = (const float*)d_in[19];
    const float* fcb     = (const float*)d_in[20];
    const float* fcfW    = (const float*)d_in[21];
    const float* fcfb    = (const float*)d_in[22];
    float* out = (float*)d_out;

    float* scr = (float*)d_ws;
    // encoder-phase view
    float* t2s    = scr;                        // 4,063,232 f
    float* g_enc  = scr + 4063232;              // 1,048,576 f
    float* hc_enc = scr + 5111808;              //   524,288 f
    f16*   Ahi    = (f16*)(scr + 5636096);      //   393,216 h
    f16*   Alo    = Ahi + 393216;               //   393,216 h
    // decoder-phase view (encoder scratch dead by then)
    float* V      = scr;                        // 8,126,464 f
    float* gu     = scr + 8126464;              // 1,310,720 f
    float* ctx    = scr + 9437184;              //   262,144 f
    float* hc_dec = scr + 9699328;              //   524,288 f
    f16*   hdhi   = (f16*)(scr + 10223616);     //   524,288 h
    f16*   hdlo   = hdhi + 524288;              //   524,288 h
    // persistent
    float* pers   = scr + 10747904;
    f16* eWhi  = (f16*)pers;                    // 1,572,864 h
    f16* eWlo  = eWhi + 1572864;
    f16* dWchi = eWlo + 1572864;                // 2,621,440 h
    f16* dWclo = dWchi + 2621440;
    f16* Vwhi  = dWclo + 2621440;               //   262,144 h
    f16* Vwlo  = Vwhi + 262144;
    f16* enchi = Vwlo + 262144;                 // 8,126,464 h
    f16* enclo = enchi + 8126464;
    float* ebcomb = (float*)(enclo + 8126464);  // 2048 f
    float* dbias  = ebcomb + 2048;              // 2560 f

    hipLaunchKernelGGL(prep_kernel, dim3(512), dim3(256), 0, stream,
                       eWih, eWhh, ebih, ebhh, dW1, dWhh, dbih, dbhh,
                       eWhi, eWlo, dWchi, dWclo, Vwhi, Vwlo, ebcomb, dbias);
    hipLaunchKernelGGL(t2s_kernel, dim3(BATCH), dim3(256), 0, stream, inputs, eWd, ebd, t2s);

    // -------- encoder --------
    for (int t = 0; t < TM1; t++) {
        hipLaunchKernelGGL(enc_step_kernel, dim3(BATCH), dim3(256), 0, stream,
                           inputs, t2s, eWc, ebc, eWa, eba, g_enc, hc_enc,
                           Ahi, Alo, enchi, enclo, hc_dec, hdhi, hdlo, t);
        hipLaunchKernelGGL(gemm3f, dim3(32, 8), dim3(256), 0, stream,
                           Ahi, Alo, 768, eWhi, eWlo, 768, ebcomb,
                           g_enc, 2048, 768, 1 << 30);
    }
    hipLaunchKernelGGL(enc_step_kernel, dim3(BATCH), dim3(256), 0, stream,
                       inputs, t2s, eWc, ebc, eWa, eba, g_enc, hc_enc,
                       Ahi, Alo, enchi, enclo, hc_dec, hdhi, hdlo, TM1);

    // -------- V = enc_out @ dec_W1[:,1024:]^T + b1 --------
    hipLaunchKernelGGL(gemm3f, dim3(8, 248), dim3(256), 0, stream,
                       enchi, enclo, 512, Vwhi, Vwlo, 512, db1,
                       V, 512, 512, 1 << 30);

    // -------- decoder --------
    for (int t = 0; t < TM1; t++) {
        hipLaunchKernelGGL(gemm3f, dim3(40, 8), dim3(256), 0, stream,
                           hdhi, hdlo, 1024, dWchi, dWclo, 1024, dbias,
                           gu, 2560, 1024, 512);
        hipLaunchKernelGGL(dec_step_kernel, dim3(BATCH), dim3(256), 0, stream,
                           inputs, V, dW2, db2, enchi, enclo, fcW, fcb, dWih,
                           gu, hc_dec, hdhi, hdlo, ctx, t);
    }

    hipLaunchKernelGGL(final_kernel, dim3(BATCH), dim3(256), 0, stream,
                       hc_dec, ctx, fcfW, fcfb, out);
}

// Round 6
// 2257.056 us; speedup vs baseline: 3.4505x; 1.0020x over previous
//
#include <hip/hip_runtime.h>
#include <math.h>

#define BATCH 512
#define TM1   31
#define DIMD  256

typedef _Float16 f16;
typedef _Float16 half8 __attribute__((ext_vector_type(8)));
typedef float floatx16 __attribute__((ext_vector_type(16)));

__device__ __forceinline__ float sigmf(float x) { return 1.f / (1.f + __expf(-x)); }

__device__ __forceinline__ float tanh_fast(float x) {
    float ax = fabsf(x);
    float t  = __expf(-2.f * ax);
    float r  = (1.f - t) / (1.f + t);
    return copysignf(r, x);
}

__device__ __forceinline__ void split16(float x, f16* hi, f16* lo) {
    f16 h = (f16)x;
    *hi = h;
    *lo = (f16)(x - (float)h);
}

__device__ __forceinline__ float blockReduceSum256(float v, float* sred) {
#pragma unroll
    for (int m = 32; m > 0; m >>= 1) v += __shfl_xor(v, m);
    __syncthreads();
    if ((threadIdx.x & 63) == 0) sred[threadIdx.x >> 6] = v;
    __syncthreads();
    return sred[0] + sred[1] + sred[2] + sred[3];
}

__device__ __forceinline__ float blockReduceMax256(float v, float* sred) {
#pragma unroll
    for (int m = 32; m > 0; m >>= 1) v = fmaxf(v, __shfl_xor(v, m));
    __syncthreads();
    if ((threadIdx.x & 63) == 0) sred[threadIdx.x >> 6] = v;
    __syncthreads();
    return fmaxf(fmaxf(sred[0], sred[1]), fmaxf(sred[2], sred[3]));
}

// ---------------------------------------------------------------------------
// prep + t2s fused (independent work): block b computes t2s for batch b;
// all blocks also grid-stride the weight splits.
// ---------------------------------------------------------------------------
__global__ __launch_bounds__(256) void prep_t2s_kernel(
    const float* __restrict__ inputs,
    const float* __restrict__ eWih, const float* __restrict__ eWhh,
    const float* __restrict__ ebih, const float* __restrict__ ebhh,
    const float* __restrict__ dW1,  const float* __restrict__ dWhh,
    const float* __restrict__ dbih, const float* __restrict__ dbhh,
    const float* __restrict__ Wd,   const float* __restrict__ bd,
    f16* __restrict__ eWhi, f16* __restrict__ eWlo,
    f16* __restrict__ dWchi, f16* __restrict__ dWclo,
    f16* __restrict__ Vwhi, f16* __restrict__ Vwlo,
    float* __restrict__ ebcomb, float* __restrict__ dbias,
    float* __restrict__ t2s)
{
    __shared__ float sX[TM1 * DIMD];
    __shared__ float sWd[TM1 * TM1];
    int b = blockIdx.x, tid = threadIdx.x;
    int idx = b * 256 + tid;
    const int stride = 512 * 256;

    // ---- t2s for batch b ----
    for (int i = tid; i < TM1 * DIMD; i += 256) {
        int tt = i >> 8, d = i & 255;
        sX[i] = inputs[((size_t)b * TM1 + tt) * 257 + 1 + d];
    }
    for (int i = tid; i < TM1 * TM1; i += 256) sWd[i] = Wd[i];
    __syncthreads();
    int d = tid;
    for (int s = 0; s < TM1; s++) {
        float acc = bd[s];
        for (int tt = 0; tt < TM1; tt++) acc += sX[tt * DIMD + d] * sWd[s * TM1 + tt];
        t2s[((size_t)b * TM1 + s) * DIMD + d] = acc;
    }

    // ---- weight splits (grid-stride) ----
    for (int i = idx; i < 2048 * 768; i += stride) {
        int n = i / 768, k = i - n * 768;
        float v = (k < 256) ? eWih[n * 256 + k] : eWhh[n * 512 + (k - 256)];
        split16(v, &eWhi[i], &eWlo[i]);
    }
    for (int i = idx; i < 2560 * 1024; i += stride) {
        int n = i >> 10, k = i & 1023;
        float v;
        if (n < 512)      v = dW1[n * 1536 + k];
        else if (k < 512) v = dWhh[(n - 512) * 512 + k];
        else              v = 0.f;
        split16(v, &dWchi[i], &dWclo[i]);
    }
    for (int i = idx; i < 512 * 512; i += stride) {
        int n = i >> 9, k = i & 511;
        split16(dW1[n * 1536 + 1024 + k], &Vwhi[i], &Vwlo[i]);
    }
    for (int i = idx; i < 2048; i += stride) ebcomb[i] = ebih[i] + ebhh[i];
    for (int i = idx; i < 2560; i += stride)
        dbias[i] = (i < 512) ? 0.f : (dbih[i - 512] + dbhh[i - 512]);
}

// ---------------------------------------------------------------------------
// fp16x3 fused MFMA GEMM (validated R3/R5). 1-D grid:
//   m_tile = bid / NT,  n_tile_base = bid % NT, n_tile = base + r*NT (r<NREP)
// NT % 8 == 0 puts all m-blocks of an n-tile on one XCD (bid%8 == n%8) so the
// weight slice stays L2-resident across the 31 step dispatches. NREP>1 (with
// NT==1) makes one block sweep several n-tiles reusing its A tile (V-gemm).
// kend = (n0 >= nsplit) ? 512 : K.
// ---------------------------------------------------------------------------
__global__ __launch_bounds__(256) void gemm3f(
    const f16* __restrict__ Ahi, const f16* __restrict__ Alo, int lda,
    const f16* __restrict__ Whi, const f16* __restrict__ Wlo, int ldw,
    const float* __restrict__ bias, float* __restrict__ C, int ldc,
    int K, int nsplit, int NT, int NREP)
{
    __shared__ f16 sAh[64 * 64];
    __shared__ f16 sAl[64 * 64];
    __shared__ f16 sWh[64 * 64];
    __shared__ f16 sWl[64 * 64];
    int tid = threadIdx.x, bid = blockIdx.x;
    int m0 = (bid / NT) * 64;
    int nbase = bid % NT;
    int lane = tid & 63, wid = tid >> 6;
    int wm = wid >> 1, wn = wid & 1;
    int rl = lane & 31, kq = lane >> 5;

    int sr = tid >> 2;
    int g0 = (tid & 3) * 2;
    int s0 = sr * 64 + ((g0 ^ (sr & 7)) * 8);
    int s1 = sr * 64 + (((g0 + 1) ^ (sr & 7)) * 8);
    int arow = (wm * 32 + rl) * 64;
    int wrow = (wn * 32 + rl) * 64;
    int sw = (rl & 7);

    const f16* pAh = Ahi + (size_t)(m0 + sr) * lda + g0 * 8;
    const f16* pAl = Alo + (size_t)(m0 + sr) * lda + g0 * 8;

    for (int r = 0; r < NREP; ++r) {
        int n0 = (nbase + r * NT) * 64;
        int kend = (n0 >= nsplit) ? 512 : K;
        const f16* pWh = Whi + (size_t)(n0 + sr) * ldw + g0 * 8;
        const f16* pWl = Wlo + (size_t)(n0 + sr) * ldw + g0 * 8;

        float4 rAh0 = *(const float4*)(pAh);
        float4 rAh1 = *(const float4*)(pAh + 8);
        float4 rAl0 = *(const float4*)(pAl);
        float4 rAl1 = *(const float4*)(pAl + 8);
        float4 rWh0 = *(const float4*)(pWh);
        float4 rWh1 = *(const float4*)(pWh + 8);
        float4 rWl0 = *(const float4*)(pWl);
        float4 rWl1 = *(const float4*)(pWl + 8);

        floatx16 acc = {};

        for (int k0 = 0; k0 < kend; k0 += 64) {
            __syncthreads();
            *(float4*)&sAh[s0] = rAh0; *(float4*)&sAh[s1] = rAh1;
            *(float4*)&sAl[s0] = rAl0; *(float4*)&sAl[s1] = rAl1;
            *(float4*)&sWh[s0] = rWh0; *(float4*)&sWh[s1] = rWh1;
            *(float4*)&sWl[s0] = rWl0; *(float4*)&sWl[s1] = rWl1;
            __syncthreads();
            int kn = k0 + 64;
            if (kn < kend) {
                rAh0 = *(const float4*)(pAh + kn); rAh1 = *(const float4*)(pAh + kn + 8);
                rAl0 = *(const float4*)(pAl + kn); rAl1 = *(const float4*)(pAl + kn + 8);
                rWh0 = *(const float4*)(pWh + kn); rWh1 = *(const float4*)(pWh + kn + 8);
                rWl0 = *(const float4*)(pWl + kn); rWl1 = *(const float4*)(pWl + kn + 8);
            }
#pragma unroll
            for (int ks = 0; ks < 64; ks += 16) {
                int lg = (ks >> 3) + kq;
                int off = ((lg ^ sw) * 8);
                half8 ah = *(const half8*)&sAh[arow + off];
                half8 al = *(const half8*)&sAl[arow + off];
                half8 wh = *(const half8*)&sWh[wrow + off];
                half8 wl = *(const half8*)&sWl[wrow + off];
                acc = __builtin_amdgcn_mfma_f32_32x32x16_f16(ah, wh, acc, 0, 0, 0);
                acc = __builtin_amdgcn_mfma_f32_32x32x16_f16(ah, wl, acc, 0, 0, 0);
                acc = __builtin_amdgcn_mfma_f32_32x32x16_f16(al, wh, acc, 0, 0, 0);
            }
        }

        int col = n0 + wn * 32 + rl;
        float bv = bias[col];
#pragma unroll
        for (int rr = 0; rr < 16; ++rr) {
            int row = m0 + wm * 32 + (rr & 3) + 8 * (rr >> 2) + 4 * kq;
            C[(size_t)row * ldc + col] = acc[rr] + bv;
        }
    }
}

// ---------------------------------------------------------------------------
// Encoder step: 512 blocks, one batch per block. Finalize LSTM t-1, then
// attention t. (64-block variant measured 48us @2.4% occupancy — keep 512.)
// ---------------------------------------------------------------------------
__global__ __launch_bounds__(256) void enc_step_kernel(
    const float* __restrict__ inputs, const float* __restrict__ t2s,
    const float* __restrict__ Wc, const float* __restrict__ bc,
    const float* __restrict__ Wa, const float* __restrict__ ba,
    const float* __restrict__ g, float* __restrict__ hc,
    f16* __restrict__ Ahi, f16* __restrict__ Alo,
    f16* __restrict__ enchi, f16* __restrict__ enclo,
    float* __restrict__ hc_dec, f16* __restrict__ hdhi, f16* __restrict__ hdlo,
    int t) {
    __shared__ float sh_hc[1024];
    __shared__ float t1s[32];
    __shared__ float sred[4];
    int b = blockIdx.x, tid = threadIdx.x;

    if (t > 0) {
        for (int e = tid; e < 512; e += 256) {
            float gi = g[b * 2048 + e];
            float gf = g[b * 2048 + 512 + e];
            float gg = g[b * 2048 + 1024 + e];
            float go = g[b * 2048 + 1536 + e];
            float cp = hc[b * 1024 + 512 + e];
            float c2 = sigmf(gf) * cp + sigmf(gi) * tanh_fast(gg);
            float h2 = sigmf(go) * tanh_fast(c2);
            hc[b * 1024 + e] = h2;
            hc[b * 1024 + 512 + e] = c2;
            sh_hc[e] = h2;
            sh_hc[512 + e] = c2;
            size_t eo = ((size_t)b * TM1 + (t - 1)) * 512 + e;
            split16(h2, &enchi[eo], &enclo[eo]);
        }
    } else {
        for (int j = tid; j < 1024; j += 256) { sh_hc[j] = 0.f; hc[b * 1024 + j] = 0.f; }
    }
    if (t == TM1) {
        for (int j = tid; j < 1024; j += 256) {
            hc_dec[b * 1024 + j] = 0.f;
            hdhi[b * 1024 + j] = (f16)0.f;
            hdlo[b * 1024 + j] = (f16)0.f;
        }
        return;
    }
    __syncthreads();

    if (tid < 248) {
        int s = tid >> 3, l8 = tid & 7;
        const float* wrow = Wc + s * 1024;
        float p = 0.f;
        for (int j = l8 * 4; j < 1024; j += 32) {
            float4 w4 = *(const float4*)(wrow + j);
            float4 h4 = *(const float4*)(&sh_hc[j]);
            p += w4.x * h4.x + w4.y * h4.y + w4.z * h4.z + w4.w * h4.w;
        }
        p += __shfl_xor(p, 1); p += __shfl_xor(p, 2); p += __shfl_xor(p, 4);
        if (l8 == 0) t1s[s] = p + bc[s];
    }
    __syncthreads();

    int d = tid;
    float sc = ba[0];
    const float* t2p = t2s + ((size_t)b * TM1) * DIMD + d;
    for (int s = 0; s < TM1; s++) sc += tanh_fast(t1s[s] + t2p[s * DIMD]) * Wa[s];
    float mx = blockReduceMax256(sc, sred);
    float ex = __expf(sc - mx);
    float sm = blockReduceSum256(ex, sred);
    float w = (ex / sm) * inputs[((size_t)b * TM1 + t) * 257 + 1 + d];
    split16(w, &Ahi[b * 768 + d], &Alo[b * 768 + d]);
    for (int j = tid; j < 512; j += 256)
        split16(sh_hc[j], &Ahi[b * 768 + 256 + j], &Alo[b * 768 + 256 + j]);
}

// ---------------------------------------------------------------------------
// Decoder step: temporal attention + ctx + y_tilde + LSTM pointwise.
// Last step (t==30) fuses the final FC: out[b] = [h31|ctx30].fcfW + fcfb.
// ctx never touches global memory.
// ---------------------------------------------------------------------------
__global__ __launch_bounds__(256) void dec_step_kernel(
    const float* __restrict__ inputs, const float* __restrict__ V,
    const float* __restrict__ W2, const float* __restrict__ b2,
    const f16* __restrict__ enchi, const f16* __restrict__ enclo,
    const float* __restrict__ fcW, const float* __restrict__ fcb,
    const float* __restrict__ Wih, const float* __restrict__ gu,
    float* __restrict__ hc, f16* __restrict__ hdhi, f16* __restrict__ hdlo,
    const float* __restrict__ fcfW, const float* __restrict__ fcfb,
    float* __restrict__ out, int t) {
    __shared__ float su[512];
    __shared__ float sw2[512];
    __shared__ float s_att[TM1];
    __shared__ float sred[4];
    int b = blockIdx.x, tid = threadIdx.x;
    const bool last = (t == TM1 - 1);
    for (int e = tid; e < 512; e += 256) {
        su[e]  = gu[(size_t)b * 2560 + e];
        sw2[e] = W2[e];
    }
    __syncthreads();
    if (tid < 248) {
        int tp = tid >> 3, l8 = tid & 7;
        const float* vrow = V + ((size_t)b * TM1 + tp) * 512;
        float p = 0.f;
        for (int j = l8 * 4; j < 512; j += 32) {
            float4 v4 = *(const float4*)(vrow + j);
            p += tanh_fast(su[j + 0] + v4.x) * sw2[j + 0]
               + tanh_fast(su[j + 1] + v4.y) * sw2[j + 1]
               + tanh_fast(su[j + 2] + v4.z) * sw2[j + 2]
               + tanh_fast(su[j + 3] + v4.w) * sw2[j + 3];
        }
        p += __shfl_xor(p, 1); p += __shfl_xor(p, 2); p += __shfl_xor(p, 4);
        if (l8 == 0) s_att[tp] = p + b2[0];
    }
    __syncthreads();
    if (tid < 64) {
        float v = (tid < TM1) ? s_att[tid] : -3.4e38f;
        float m = v;
#pragma unroll
        for (int k = 32; k > 0; k >>= 1) m = fmaxf(m, __shfl_xor(m, k));
        float e = (tid < TM1) ? __expf(v - m) : 0.f;
        float s = e;
#pragma unroll
        for (int k = 32; k > 0; k >>= 1) s += __shfl_xor(s, k);
        if (tid < TM1) s_att[tid] = e / s;
    }
    __syncthreads();

    float part = 0.f;     // ctx . fcW
    float pctx = 0.f;     // ctx . fcfW[512:]  (only used at last step)
#pragma unroll
    for (int r = 0; r < 2; r++) {
        int e = tid + r * 256;
        float cx = 0.f;
        const f16* eh = enchi + (size_t)b * TM1 * 512 + e;
        const f16* el = enclo + (size_t)b * TM1 * 512 + e;
        for (int tp = 0; tp < TM1; tp++)
            cx += s_att[tp] * ((float)eh[tp * 512] + (float)el[tp * 512]);
        part += cx * fcW[e];
        if (last) pctx += cx * fcfW[512 + e];
    }
    float y = inputs[((size_t)b * TM1 + t) * 257];
    float ysum = blockReduceSum256(part, sred);
    float y_til = ysum + y * fcW[512] + fcb[0];

    float ph = 0.f;       // h31 . fcfW[:512]
    for (int e = tid; e < 512; e += 256) {
        float gi = gu[(size_t)b * 2560 + 512 + e]  + y_til * Wih[e];
        float gf = gu[(size_t)b * 2560 + 1024 + e] + y_til * Wih[512 + e];
        float gg = gu[(size_t)b * 2560 + 1536 + e] + y_til * Wih[1024 + e];
        float go = gu[(size_t)b * 2560 + 2048 + e] + y_til * Wih[1536 + e];
        float cp = hc[b * 1024 + 512 + e];
        float c2 = sigmf(gf) * cp + sigmf(gi) * tanh_fast(gg);
        float h2 = sigmf(go) * tanh_fast(c2);
        if (!last) {
            hc[b * 1024 + e] = h2;
            hc[b * 1024 + 512 + e] = c2;
            split16(h2, &hdhi[(size_t)b * 1024 + e], &hdlo[(size_t)b * 1024 + e]);
            split16(c2, &hdhi[(size_t)b * 1024 + 512 + e], &hdlo[(size_t)b * 1024 + 512 + e]);
        } else {
            ph += h2 * fcfW[e];
        }
    }
    if (last) {
        float s = blockReduceSum256(ph + pctx, sred);
        if (tid == 0) out[b] = s + fcfb[0];
    }
}

extern "C" void kernel_launch(void* const* d_in, const int* in_sizes, int n_in,
                              void* d_out, int out_size, void* d_ws, size_t ws_size,
                              hipStream_t stream) {
    const float* inputs  = (const float*)d_in[0];
    const float* eWih    = (const float*)d_in[1];
    const float* eWhh    = (const float*)d_in[2];
    const float* ebih    = (const float*)d_in[3];
    const float* ebhh    = (const float*)d_in[4];
    const float* eWc     = (const float*)d_in[5];
    const float* ebc     = (const float*)d_in[6];
    const float* eWd     = (const float*)d_in[7];
    const float* ebd     = (const float*)d_in[8];
    const float* eWa     = (const float*)d_in[9];
    const float* eba     = (const float*)d_in[10];
    const float* dW1     = (const float*)d_in[11];
    const float* db1     = (const float*)d_in[12];
    const float* dW2     = (const float*)d_in[13];
    const float* db2     = (const float*)d_in[14];
    const float* dWih    = (const float*)d_in[15];
    const float* dWhh    = (const float*)d_in[16];
    const float* dbih    = (const float*)d_in[17];
    const float* dbhh    = (const float*)d_in[18];
    const float* fcW     = (const float*)d_in[19];
    const float* fcb     = (const float*)d_in[20];
    const float* fcfW    = (const float*)d_in[21];
    const float* fcfb    = (const float*)d_in[22];
    float* out = (float*)d_out;

    float* scr = (float*)d_ws;
    // encoder-phase view
    float* t2s    = scr;                        // 4,063,232 f
    float* g_enc  = scr + 4063232;              // 1,048,576 f
    float* hc_enc = scr + 5111808;              //   524,288 f
    f16*   Ahi    = (f16*)(scr + 5636096);      //   393,216 h
    f16*   Alo    = Ahi + 393216;               //   393,216 h
    // decoder-phase view (encoder scratch dead by then)
    float* V      = scr;                        // 8,126,464 f
    float* gu     = scr + 8126464;              // 1,310,720 f
    float* hc_dec = scr + 9699328;              //   524,288 f
    f16*   hdhi   = (f16*)(scr + 10223616);     //   524,288 h
    f16*   hdlo   = hdhi + 524288;              //   524,288 h
    // persistent
    float* pers   = scr + 10747904;
    f16* eWhi  = (f16*)pers;                    // 1,572,864 h
    f16* eWlo  = eWhi + 1572864;
    f16* dWchi = eWlo + 1572864;                // 2,621,440 h
    f16* dWclo = dWchi + 2621440;
    f16* Vwhi  = dWclo + 2621440;               //   262,144 h
    f16* Vwlo  = Vwhi + 262144;
    f16* enchi = Vwlo + 262144;                 // 8,126,464 h
    f16* enclo = enchi + 8126464;
    float* ebcomb = (float*)(enclo + 8126464);  // 2048 f
    float* dbias  = ebcomb + 2048;              // 2560 f

    hipLaunchKernelGGL(prep_t2s_kernel, dim3(512), dim3(256), 0, stream,
                       inputs, eWih, eWhh, ebih, ebhh, dW1, dWhh, dbih, dbhh,
                       eWd, ebd, eWhi, eWlo, dWchi, dWclo, Vwhi, Vwlo,
                       ebcomb, dbias, t2s);

    // -------- encoder --------
    for (int t = 0; t < TM1; t++) {
        hipLaunchKernelGGL(enc_step_kernel, dim3(BATCH), dim3(256), 0, stream,
                           inputs, t2s, eWc, ebc, eWa, eba, g_enc, hc_enc,
                           Ahi, Alo, enchi, enclo, hc_dec, hdhi, hdlo, t);
        // M=512,N=2048,K=768: grid 8m x 32n; NT=32 (n%8 == bid%8 -> XCD-resident W)
        hipLaunchKernelGGL(gemm3f, dim3(256), dim3(256), 0, stream,
                           Ahi, Alo, 768, eWhi, eWlo, 768, ebcomb,
                           g_enc, 2048, 768, 1 << 30, 32, 1);
    }
    hipLaunchKernelGGL(enc_step_kernel, dim3(BATCH), dim3(256), 0, stream,
                       inputs, t2s, eWc, ebc, eWa, eba, g_enc, hc_enc,
                       Ahi, Alo, enchi, enclo, hc_dec, hdhi, hdlo, TM1);

    // -------- V = enc_out @ dec_W1[:,1024:]^T + b1 --------
    // M=15872: 248 blocks; each sweeps all 8 n-tiles (NREP=8) reusing its A tile.
    hipLaunchKernelGGL(gemm3f, dim3(248), dim3(256), 0, stream,
                       enchi, enclo, 512, Vwhi, Vwlo, 512, db1,
                       V, 512, 512, 1 << 30, 1, 8);

    // -------- decoder --------
    for (int t = 0; t < TM1; t++) {
        // M=512,N=2560: grid 8m x 40n; NT=40; K=1024 for n<512 ([h|c]), 512 above
        hipLaunchKernelGGL(gemm3f, dim3(320), dim3(256), 0, stream,
                           hdhi, hdlo, 1024, dWchi, dWclo, 1024, dbias,
                           gu, 2560, 1024, 512, 40, 1);
        hipLaunchKernelGGL(dec_step_kernel, dim3(BATCH), dim3(256), 0, stream,
                           inputs, V, dW2, db2, enchi, enclo, fcW, fcb, dWih,
                           gu, hc_dec, hdhi, hdlo, fcfW, fcfb, out, t);
    }
}

// Round 7
// 1854.217 us; speedup vs baseline: 4.2001x; 1.2173x over previous
//
#include <hip/hip_runtime.h>
#include <math.h>

#define BATCH 512
#define TM1   31
#define DIMD  256

typedef _Float16 f16;
typedef _Float16 half8 __attribute__((ext_vector_type(8)));
typedef float floatx16 __attribute__((ext_vector_type(16)));

__device__ __forceinline__ float sigmf(float x) { return 1.f / (1.f + __expf(-x)); }

__device__ __forceinline__ float tanh_fast(float x) {
    float ax = fabsf(x);
    float t  = __expf(-2.f * ax);
    float r  = (1.f - t) / (1.f + t);
    return copysignf(r, x);
}

__device__ __forceinline__ void split16(float x, f16* hi, f16* lo) {
    f16 h = (f16)x;
    *hi = h;
    *lo = (f16)(x - (float)h);
}

__device__ __forceinline__ float blockReduceSum256(float v, float* sred) {
#pragma unroll
    for (int m = 32; m > 0; m >>= 1) v += __shfl_xor(v, m);
    __syncthreads();
    if ((threadIdx.x & 63) == 0) sred[threadIdx.x >> 6] = v;
    __syncthreads();
    return sred[0] + sred[1] + sred[2] + sred[3];
}

__device__ __forceinline__ float blockReduceMax256(float v, float* sred) {
#pragma unroll
    for (int m = 32; m > 0; m >>= 1) v = fmaxf(v, __shfl_xor(v, m));
    __syncthreads();
    if ((threadIdx.x & 63) == 0) sred[threadIdx.x >> 6] = v;
    __syncthreads();
    return fmaxf(fmaxf(sred[0], sred[1]), fmaxf(sred[2], sred[3]));
}

// ---------------------------------------------------------------------------
// prep + t2s fused: block b computes t2s for batch b; all blocks grid-stride
// the weight hi/lo splits (weights only — activations are stored plain fp16).
// ---------------------------------------------------------------------------
__global__ __launch_bounds__(256) void prep_t2s_kernel(
    const float* __restrict__ inputs,
    const float* __restrict__ eWih, const float* __restrict__ eWhh,
    const float* __restrict__ ebih, const float* __restrict__ ebhh,
    const float* __restrict__ dW1,  const float* __restrict__ dWhh,
    const float* __restrict__ dbih, const float* __restrict__ dbhh,
    const float* __restrict__ Wd,   const float* __restrict__ bd,
    f16* __restrict__ eWhi, f16* __restrict__ eWlo,
    f16* __restrict__ dWchi, f16* __restrict__ dWclo,
    f16* __restrict__ Vwhi, f16* __restrict__ Vwlo,
    float* __restrict__ ebcomb, float* __restrict__ dbias,
    float* __restrict__ t2s)
{
    __shared__ float sX[TM1 * DIMD];
    __shared__ float sWd[TM1 * TM1];
    int b = blockIdx.x, tid = threadIdx.x;
    int idx = b * 256 + tid;
    const int stride = 512 * 256;

    for (int i = tid; i < TM1 * DIMD; i += 256) {
        int tt = i >> 8, d = i & 255;
        sX[i] = inputs[((size_t)b * TM1 + tt) * 257 + 1 + d];
    }
    for (int i = tid; i < TM1 * TM1; i += 256) sWd[i] = Wd[i];
    __syncthreads();
    int d = tid;
    for (int s = 0; s < TM1; s++) {
        float acc = bd[s];
        for (int tt = 0; tt < TM1; tt++) acc += sX[tt * DIMD + d] * sWd[s * TM1 + tt];
        t2s[((size_t)b * TM1 + s) * DIMD + d] = acc;
    }

    for (int i = idx; i < 2048 * 768; i += stride) {
        int n = i / 768, k = i - n * 768;
        float v = (k < 256) ? eWih[n * 256 + k] : eWhh[n * 512 + (k - 256)];
        split16(v, &eWhi[i], &eWlo[i]);
    }
    for (int i = idx; i < 2560 * 1024; i += stride) {
        int n = i >> 10, k = i & 1023;
        float v;
        if (n < 512)      v = dW1[n * 1536 + k];
        else if (k < 512) v = dWhh[(n - 512) * 512 + k];
        else              v = 0.f;
        split16(v, &dWchi[i], &dWclo[i]);
    }
    for (int i = idx; i < 512 * 512; i += stride) {
        int n = i >> 9, k = i & 511;
        split16(dW1[n * 1536 + 1024 + k], &Vwhi[i], &Vwlo[i]);
    }
    for (int i = idx; i < 2048; i += stride) ebcomb[i] = ebih[i] + ebhh[i];
    for (int i = idx; i < 2560; i += stride)
        dbias[i] = (i < 512) ? 0.f : (dbih[i - 512] + dbhh[i - 512]);
}

// ---------------------------------------------------------------------------
// fp16x2 MFMA GEMM with split-K: C_ks[m,n] = sum_{k in slice ks} A[m,k]*
// (Whi[n,k]+Wlo[n,k]) (+bias if ks==0). A is plain fp16 (activations).
// 1-D grid: n = bid%NT, m = (bid/NT)%MT, ks = bid/(NT*MT). Slice ks writes
// C + ks*Cstride (separate buffers; consumer sums). NT%8==0 keeps an n-tile's
// blocks on one XCD (weight slice L2-resident across the 31 step dispatches).
// NREP>1: block sweeps n-tiles (nbase + r*NT) reusing its A tile (V-gemm).
// Kfull = (n0 >= nsplit) ? 512 : K; slice width = Kfull/KS (%64 == 0).
// 64x64 tile, 4 waves of 32x32x16 MFMA, XOR-swizzled LDS, reg prefetch.
// ---------------------------------------------------------------------------
__global__ __launch_bounds__(256) void gemm2f(
    const f16* __restrict__ Ahi, int lda,
    const f16* __restrict__ Whi, const f16* __restrict__ Wlo, int ldw,
    const float* __restrict__ bias, float* __restrict__ C, int ldc,
    long long Cstride, int K, int nsplit, int NT, int MT, int KS, int NREP)
{
    __shared__ f16 sAh[64 * 64];
    __shared__ f16 sWh[64 * 64];
    __shared__ f16 sWl[64 * 64];
    int tid = threadIdx.x, bid = blockIdx.x;
    int nbase = bid % NT;
    int m0 = ((bid / NT) % MT) * 64;
    int ks = bid / (NT * MT);
    int lane = tid & 63, wid = tid >> 6;
    int wm = wid >> 1, wn = wid & 1;
    int rl = lane & 31, kq = lane >> 5;

    int sr = tid >> 2;
    int g0 = (tid & 3) * 2;
    int s0 = sr * 64 + ((g0 ^ (sr & 7)) * 8);
    int s1 = sr * 64 + (((g0 + 1) ^ (sr & 7)) * 8);
    int arow = (wm * 32 + rl) * 64;
    int wrow = (wn * 32 + rl) * 64;
    int sw = (rl & 7);

    const f16* pAh = Ahi + (size_t)(m0 + sr) * lda + g0 * 8;
    float* Cp = C + (size_t)ks * Cstride;

    for (int r = 0; r < NREP; ++r) {
        int n0 = (nbase + r * NT) * 64;
        int Kfull = (n0 >= nsplit) ? 512 : K;
        int ksz = Kfull / KS;
        int kbeg = ks * ksz, kend = kbeg + ksz;
        const f16* pWh = Whi + (size_t)(n0 + sr) * ldw + g0 * 8;
        const f16* pWl = Wlo + (size_t)(n0 + sr) * ldw + g0 * 8;

        float4 rAh0 = *(const float4*)(pAh + kbeg);
        float4 rAh1 = *(const float4*)(pAh + kbeg + 8);
        float4 rWh0 = *(const float4*)(pWh + kbeg);
        float4 rWh1 = *(const float4*)(pWh + kbeg + 8);
        float4 rWl0 = *(const float4*)(pWl + kbeg);
        float4 rWl1 = *(const float4*)(pWl + kbeg + 8);

        floatx16 acc = {};

        for (int k0 = kbeg; k0 < kend; k0 += 64) {
            __syncthreads();
            *(float4*)&sAh[s0] = rAh0; *(float4*)&sAh[s1] = rAh1;
            *(float4*)&sWh[s0] = rWh0; *(float4*)&sWh[s1] = rWh1;
            *(float4*)&sWl[s0] = rWl0; *(float4*)&sWl[s1] = rWl1;
            __syncthreads();
            int kn = k0 + 64;
            if (kn < kend) {
                rAh0 = *(const float4*)(pAh + kn); rAh1 = *(const float4*)(pAh + kn + 8);
                rWh0 = *(const float4*)(pWh + kn); rWh1 = *(const float4*)(pWh + kn + 8);
                rWl0 = *(const float4*)(pWl + kn); rWl1 = *(const float4*)(pWl + kn + 8);
            }
#pragma unroll
            for (int kk = 0; kk < 64; kk += 16) {
                int lg = (kk >> 3) + kq;
                int off = ((lg ^ sw) * 8);
                half8 ah = *(const half8*)&sAh[arow + off];
                half8 wh = *(const half8*)&sWh[wrow + off];
                half8 wl = *(const half8*)&sWl[wrow + off];
                acc = __builtin_amdgcn_mfma_f32_32x32x16_f16(ah, wh, acc, 0, 0, 0);
                acc = __builtin_amdgcn_mfma_f32_32x32x16_f16(ah, wl, acc, 0, 0, 0);
            }
        }

        int col = n0 + wn * 32 + rl;
        float bv = (ks == 0) ? bias[col] : 0.f;
#pragma unroll
        for (int rr = 0; rr < 16; ++rr) {
            int row = m0 + wm * 32 + (rr & 3) + 8 * (rr >> 2) + 4 * kq;
            Cp[(size_t)row * ldc + col] = acc[rr] + bv;
        }
    }
}

// ---------------------------------------------------------------------------
// Encoder step: 512 blocks, one batch per block. Finalize LSTM t-1 from
// g0+g1 (split-K halves), then attention t. Activations stored plain fp16.
// ---------------------------------------------------------------------------
__global__ __launch_bounds__(256) void enc_step_kernel(
    const float* __restrict__ inputs, const float* __restrict__ t2s,
    const float* __restrict__ Wc, const float* __restrict__ bc,
    const float* __restrict__ Wa, const float* __restrict__ ba,
    const float* __restrict__ g0, const float* __restrict__ g1,
    float* __restrict__ hc,
    f16* __restrict__ Ahi, f16* __restrict__ enchi,
    float* __restrict__ hc_dec, f16* __restrict__ hdhi,
    int t) {
    __shared__ float sh_hc[1024];
    __shared__ float t1s[32];
    __shared__ float sred[4];
    int b = blockIdx.x, tid = threadIdx.x;

    if (t > 0) {
        for (int e = tid; e < 512; e += 256) {
            float gi = g0[b * 2048 + e]        + g1[b * 2048 + e];
            float gf = g0[b * 2048 + 512 + e]  + g1[b * 2048 + 512 + e];
            float gg = g0[b * 2048 + 1024 + e] + g1[b * 2048 + 1024 + e];
            float go = g0[b * 2048 + 1536 + e] + g1[b * 2048 + 1536 + e];
            float cp = hc[b * 1024 + 512 + e];
            float c2 = sigmf(gf) * cp + sigmf(gi) * tanh_fast(gg);
            float h2 = sigmf(go) * tanh_fast(c2);
            hc[b * 1024 + e] = h2;
            hc[b * 1024 + 512 + e] = c2;
            sh_hc[e] = h2;
            sh_hc[512 + e] = c2;
            enchi[((size_t)b * TM1 + (t - 1)) * 512 + e] = (f16)h2;
        }
    } else {
        for (int j = tid; j < 1024; j += 256) { sh_hc[j] = 0.f; hc[b * 1024 + j] = 0.f; }
    }
    if (t == TM1) {
        for (int j = tid; j < 1024; j += 256) {
            hc_dec[b * 1024 + j] = 0.f;
            hdhi[b * 1024 + j] = (f16)0.f;
        }
        return;
    }
    __syncthreads();

    if (tid < 248) {
        int s = tid >> 3, l8 = tid & 7;
        const float* wrow = Wc + s * 1024;
        float p = 0.f;
        for (int j = l8 * 4; j < 1024; j += 32) {
            float4 w4 = *(const float4*)(wrow + j);
            float4 h4 = *(const float4*)(&sh_hc[j]);
            p += w4.x * h4.x + w4.y * h4.y + w4.z * h4.z + w4.w * h4.w;
        }
        p += __shfl_xor(p, 1); p += __shfl_xor(p, 2); p += __shfl_xor(p, 4);
        if (l8 == 0) t1s[s] = p + bc[s];
    }
    __syncthreads();

    int d = tid;
    float sc = ba[0];
    const float* t2p = t2s + ((size_t)b * TM1) * DIMD + d;
    for (int s = 0; s < TM1; s++) sc += tanh_fast(t1s[s] + t2p[s * DIMD]) * Wa[s];
    float mx = blockReduceMax256(sc, sred);
    float ex = __expf(sc - mx);
    float sm = blockReduceSum256(ex, sred);
    float w = (ex / sm) * inputs[((size_t)b * TM1 + t) * 257 + 1 + d];
    Ahi[b * 768 + d] = (f16)w;
    for (int j = tid; j < 512; j += 256)
        Ahi[b * 768 + 256 + j] = (f16)sh_hc[j];
}

// ---------------------------------------------------------------------------
// Decoder step: attention + ctx + y_tilde + LSTM pointwise; gates from
// gu0+gu1. Last step fuses final FC (ctx never hits global).
// ---------------------------------------------------------------------------
__global__ __launch_bounds__(256) void dec_step_kernel(
    const float* __restrict__ inputs, const float* __restrict__ V,
    const float* __restrict__ W2, const float* __restrict__ b2,
    const f16* __restrict__ enchi,
    const float* __restrict__ fcW, const float* __restrict__ fcb,
    const float* __restrict__ Wih,
    const float* __restrict__ gu0, const float* __restrict__ gu1,
    float* __restrict__ hc, f16* __restrict__ hdhi,
    const float* __restrict__ fcfW, const float* __restrict__ fcfb,
    float* __restrict__ out, int t) {
    __shared__ float su[512];
    __shared__ float sw2[512];
    __shared__ float s_att[TM1];
    __shared__ float sred[4];
    int b = blockIdx.x, tid = threadIdx.x;
    const bool last = (t == TM1 - 1);
    for (int e = tid; e < 512; e += 256) {
        su[e]  = gu0[(size_t)b * 2560 + e] + gu1[(size_t)b * 2560 + e];
        sw2[e] = W2[e];
    }
    __syncthreads();
    if (tid < 248) {
        int tp = tid >> 3, l8 = tid & 7;
        const float* vrow = V + ((size_t)b * TM1 + tp) * 512;
        float p = 0.f;
        for (int j = l8 * 4; j < 512; j += 32) {
            float4 v4 = *(const float4*)(vrow + j);
            p += tanh_fast(su[j + 0] + v4.x) * sw2[j + 0]
               + tanh_fast(su[j + 1] + v4.y) * sw2[j + 1]
               + tanh_fast(su[j + 2] + v4.z) * sw2[j + 2]
               + tanh_fast(su[j + 3] + v4.w) * sw2[j + 3];
        }
        p += __shfl_xor(p, 1); p += __shfl_xor(p, 2); p += __shfl_xor(p, 4);
        if (l8 == 0) s_att[tp] = p + b2[0];
    }
    __syncthreads();
    if (tid < 64) {
        float v = (tid < TM1) ? s_att[tid] : -3.4e38f;
        float m = v;
#pragma unroll
        for (int k = 32; k > 0; k >>= 1) m = fmaxf(m, __shfl_xor(m, k));
        float e = (tid < TM1) ? __expf(v - m) : 0.f;
        float s = e;
#pragma unroll
        for (int k = 32; k > 0; k >>= 1) s += __shfl_xor(s, k);
        if (tid < TM1) s_att[tid] = e / s;
    }
    __syncthreads();

    float part = 0.f;
    float pctx = 0.f;
#pragma unroll
    for (int r = 0; r < 2; r++) {
        int e = tid + r * 256;
        float cx = 0.f;
        const f16* eh = enchi + (size_t)b * TM1 * 512 + e;
        for (int tp = 0; tp < TM1; tp++)
            cx += s_att[tp] * (float)eh[tp * 512];
        part += cx * fcW[e];
        if (last) pctx += cx * fcfW[512 + e];
    }
    float y = inputs[((size_t)b * TM1 + t) * 257];
    float ysum = blockReduceSum256(part, sred);
    float y_til = ysum + y * fcW[512] + fcb[0];

    float ph = 0.f;
    for (int e = tid; e < 512; e += 256) {
        float gi = gu0[(size_t)b * 2560 + 512 + e]  + gu1[(size_t)b * 2560 + 512 + e]  + y_til * Wih[e];
        float gf = gu0[(size_t)b * 2560 + 1024 + e] + gu1[(size_t)b * 2560 + 1024 + e] + y_til * Wih[512 + e];
        float gg = gu0[(size_t)b * 2560 + 1536 + e] + gu1[(size_t)b * 2560 + 1536 + e] + y_til * Wih[1024 + e];
        float go = gu0[(size_t)b * 2560 + 2048 + e] + gu1[(size_t)b * 2560 + 2048 + e] + y_til * Wih[1536 + e];
        float cp = hc[b * 1024 + 512 + e];
        float c2 = sigmf(gf) * cp + sigmf(gi) * tanh_fast(gg);
        float h2 = sigmf(go) * tanh_fast(c2);
        if (!last) {
            hc[b * 1024 + e] = h2;
            hc[b * 1024 + 512 + e] = c2;
            hdhi[(size_t)b * 1024 + e] = (f16)h2;
            hdhi[(size_t)b * 1024 + 512 + e] = (f16)c2;
        } else {
            ph += h2 * fcfW[e];
        }
    }
    if (last) {
        float s = blockReduceSum256(ph + pctx, sred);
        if (tid == 0) out[b] = s + fcfb[0];
    }
}

extern "C" void kernel_launch(void* const* d_in, const int* in_sizes, int n_in,
                              void* d_out, int out_size, void* d_ws, size_t ws_size,
                              hipStream_t stream) {
    const float* inputs  = (const float*)d_in[0];
    const float* eWih    = (const float*)d_in[1];
    const float* eWhh    = (const float*)d_in[2];
    const float* ebih    = (const float*)d_in[3];
    const float* ebhh    = (const float*)d_in[4];
    const float* eWc     = (const float*)d_in[5];
    const float* ebc     = (const float*)d_in[6];
    const float* eWd     = (const float*)d_in[7];
    const float* ebd     = (const float*)d_in[8];
    const float* eWa     = (const float*)d_in[9];
    const float* eba     = (const float*)d_in[10];
    const float* dW1     = (const float*)d_in[11];
    const float* db1     = (const float*)d_in[12];
    const float* dW2     = (const float*)d_in[13];
    const float* db2     = (const float*)d_in[14];
    const float* dWih    = (const float*)d_in[15];
    const float* dWhh    = (const float*)d_in[16];
    const float* dbih    = (const float*)d_in[17];
    const float* dbhh    = (const float*)d_in[18];
    const float* fcW     = (const float*)d_in[19];
    const float* fcb     = (const float*)d_in[20];
    const float* fcfW    = (const float*)d_in[21];
    const float* fcfb    = (const float*)d_in[22];
    float* out = (float*)d_out;

    float* scr = (float*)d_ws;
    // ---- union region (11,534,336 f) ----
    // encoder view:
    float* t2s    = scr;                        // 4,063,232 f
    float* g0e    = scr + 4063232;              // 1,048,576 f
    float* g1e    = scr + 5111808;              // 1,048,576 f
    float* hc_enc = scr + 6160384;              //   524,288 f
    f16*   Ahi    = (f16*)(scr + 6684672);      //   393,216 h
    // decoder view (encoder scratch dead; hc_dec/hdhi written only at enc end):
    float* V      = scr;                        // 8,126,464 f
    float* gu0    = scr + 8126464;              // 1,310,720 f  (slice 0; Cstride -> gu1)
    float* gu1    = scr + 9437184;              // 1,310,720 f
    float* hc_dec = scr + 10747904;             //   524,288 f
    f16*   hdhi   = (f16*)(scr + 11272192);     //   524,288 h (262,144 f)
    // ---- persistent (after union) ----
    f16* fp = (f16*)(scr + 11534336);
    f16* eWhi  = fp;             fp += 1572864;
    f16* eWlo  = fp;             fp += 1572864;
    f16* dWchi = fp;             fp += 2621440;
    f16* dWclo = fp;             fp += 2621440;
    f16* Vwhi  = fp;             fp += 262144;
    f16* Vwlo  = fp;             fp += 262144;
    f16* enchi = fp;             fp += 8126464;
    float* ebcomb = (float*)(((uintptr_t)fp + 15) & ~(uintptr_t)15);
    float* dbias  = ebcomb + 2048;              // 2560 f

    hipLaunchKernelGGL(prep_t2s_kernel, dim3(512), dim3(256), 0, stream,
                       inputs, eWih, eWhh, ebih, ebhh, dW1, dWhh, dbih, dbhh,
                       eWd, ebd, eWhi, eWlo, dWchi, dWclo, Vwhi, Vwlo,
                       ebcomb, dbias, t2s);

    const long long gstride = (long long)(g1e - g0e);   // 1,048,576
    const long long ustride = (long long)(gu1 - gu0);   // 1,310,720

    // -------- encoder --------
    for (int t = 0; t < TM1; t++) {
        hipLaunchKernelGGL(enc_step_kernel, dim3(BATCH), dim3(256), 0, stream,
                           inputs, t2s, eWc, ebc, eWa, eba, g0e, g1e, hc_enc,
                           Ahi, enchi, hc_dec, hdhi, t);
        // M=512,N=2048,K=768 split-K2: NT=32, MT=8, KS=2 -> 512 blocks (2/CU)
        hipLaunchKernelGGL(gemm2f, dim3(512), dim3(256), 0, stream,
                           Ahi, 768, eWhi, eWlo, 768, ebcomb,
                           g0e, 2048, gstride, 768, 1 << 30, 32, 8, 2, 1);
    }
    hipLaunchKernelGGL(enc_step_kernel, dim3(BATCH), dim3(256), 0, stream,
                       inputs, t2s, eWc, ebc, eWa, eba, g0e, g1e, hc_enc,
                       Ahi, enchi, hc_dec, hdhi, TM1);

    // -------- V = enc_out @ dec_W1[:,1024:]^T + b1 --------
    // M=15872: NT=4, MT=248, KS=1, NREP=2 -> 992 blocks, A tile read ~4x
    hipLaunchKernelGGL(gemm2f, dim3(992), dim3(256), 0, stream,
                       enchi, 512, Vwhi, Vwlo, 512, db1,
                       V, 512, 0, 512, 1 << 30, 4, 248, 1, 2);

    // -------- decoder --------
    for (int t = 0; t < TM1; t++) {
        // M=512,N=2560 split-K2: NT=40, MT=8, KS=2 -> 640 blocks
        // n<512: K=1024 ([h|c]); n>=512: K=512 (h only, via nsplit)
        hipLaunchKernelGGL(gemm2f, dim3(640), dim3(256), 0, stream,
                           hdhi, 1024, dWchi, dWclo, 1024, dbias,
                           gu0, 2560, ustride, 1024, 512, 40, 8, 2, 1);
        hipLaunchKernelGGL(dec_step_kernel, dim3(BATCH), dim3(256), 0, stream,
                           inputs, V, dW2, db2, enchi, fcW, fcb, dWih,
                           gu0, gu1, hc_dec, hdhi, fcfW, fcfb, out, t);
    }
}